// Round 2
// baseline (149.521 us; speedup 1.0000x reference)
//
#include <hip/hip_runtime.h>
#include <hip/hip_bf16.h>
#include <stdint.h>

#define N_NODES 4096
#define IN_F 256
#define OUT_F 32
#define H 8
#define HF 256   // H*OUT_F
#define NPB 4    // nodes per block in wh_kernel
#define MAXK 128 // max neighbors per row (mean ~17)

typedef __hip_bfloat16 bf16;
__device__ __forceinline__ float b2f(bf16 v) { return __bfloat162float(v); }

// ws counters: [0]=wild bf16 count in x, [1]=E, [2]=F, [3]=G (adj structure)
// float mode: f32 iff wild>32.
// adj mode: 0=4-byte elements (int32 0/1 OR f32 0.0/1.0; test word!=0)
//           1=2-byte elements (bf16 0/1; test halfword!=0)
//           2=1-byte elements (bool bytes; test byte!=0)
__device__ __forceinline__ int is_f32_mode(const int* c) { return c[0] > 32; }
__device__ __forceinline__ int adj_mode_of(const int* c) {
    int E = c[1], F = c[2], G = c[3];
    if (E == 0) return 0;            // only byte0-of-word ever set -> int32 0/1
    if (F > 0 && G == 0) return 0;   // 0x3F80 high halves, low halves 0 -> f32 1.0
    if (F > 0) return 1;             // 0x3F80 at even halfwords too -> bf16
    return 2;                        // plain bool bytes
}

__global__ __launch_bounds__(256) void detect_kernel(
    const uint16_t* __restrict__ x, const uint32_t* __restrict__ adj,
    int* __restrict__ cnts)
{
    __shared__ int s[4];
    const int t = threadIdx.x;
    if (t < 4) s[t] = 0;
    __syncthreads();
    int wild = 0, E = 0, F = 0, G = 0;
    if (blockIdx.x == 0) {
        // bf16 view of first 2048 elements of x (~N(0,1) data)
        for (int i = t; i < 2048; i += 256) {
            uint16_t u = x[i];
            bf16 v = *(bf16*)&u;
            float f = b2f(v);
            if (!(fabsf(f) < 100.0f)) wild++;  // catches huge + NaN
        }
    }
    for (int i = blockIdx.x * 256 + t; i < 65536; i += gridDim.x * 256) {
        uint32_t w = adj[i];
        if ((w >> 8) != 0) E++;                       // bits outside byte0
        uint32_t lo = w & 0xFFFFu, hi = w >> 16;
        if (lo == 0x3F80u || hi == 0x3F80u) F++;      // bf16/f32 "1.0" pattern
        if (lo != 0) G++;                             // even-halfword nonzero
    }
    atomicAdd(&s[0], wild); atomicAdd(&s[1], E);
    atomicAdd(&s[2], F);    atomicAdd(&s[3], G);
    __syncthreads();
    if (t < 4 && s[t] != 0) atomicAdd(&cnts[t], s[t]);
}

// Wh[n][h*32+f] = sum_i x[n][i] * W[h][i][f]  (fp32 into ws),
// plus e_src[n][h], e_dst[n][h] via 32-lane shuffle reduction.
__global__ __launch_bounds__(256) void wh_kernel(
    const void* __restrict__ xv, const void* __restrict__ Wv,
    const void* __restrict__ asv, const void* __restrict__ adv,
    const int* __restrict__ cnts,
    float* __restrict__ Wh, float* __restrict__ esrc, float* __restrict__ edst)
{
    __shared__ float xl[NPB][IN_F];
    const int t = threadIdx.x;
    const int n0 = blockIdx.x * NPB;
    const int f32m = is_f32_mode(cnts);

    if (f32m) {
        const float* x = (const float*)xv;
        for (int r = 0; r < NPB; ++r) xl[r][t] = x[(size_t)(n0 + r) * IN_F + t];
    } else {
        const bf16* x = (const bf16*)xv;
        for (int r = 0; r < NPB; ++r) xl[r][t] = b2f(x[(size_t)(n0 + r) * IN_F + t]);
    }
    __syncthreads();

    const int h = t >> 5, f = t & 31;
    float acc[NPB] = {0.f, 0.f, 0.f, 0.f};
    if (f32m) {
        const float* Wp = (const float*)Wv + (size_t)h * IN_F * OUT_F + f;
        #pragma unroll 8
        for (int i = 0; i < IN_F; ++i) {
            float w = Wp[i * OUT_F];
            for (int r = 0; r < NPB; ++r) acc[r] += xl[r][i] * w;
        }
    } else {
        const bf16* Wp = (const bf16*)Wv + (size_t)h * IN_F * OUT_F + f;
        #pragma unroll 8
        for (int i = 0; i < IN_F; ++i) {
            float w = b2f(Wp[i * OUT_F]);
            for (int r = 0; r < NPB; ++r) acc[r] += xl[r][i] * w;
        }
    }

    float as, ad;
    if (f32m) { as = ((const float*)asv)[t]; ad = ((const float*)adv)[t]; }
    else      { as = b2f(((const bf16*)asv)[t]); ad = b2f(((const bf16*)adv)[t]); }

    for (int r = 0; r < NPB; ++r) {
        Wh[(size_t)(n0 + r) * HF + t] = acc[r];
        float vs = acc[r] * as, vd = acc[r] * ad;
        for (int off = 16; off > 0; off >>= 1) {
            vs += __shfl_down(vs, off, 32);
            vd += __shfl_down(vd, off, 32);
        }
        if (f == 0) {
            esrc[(size_t)(n0 + r) * H + h] = vs;
            edst[(size_t)(n0 + r) * H + h] = vd;
        }
    }
}

// Per row i: gather neighbor list, per-head softmax over ~17 logits,
// aggregate alpha*Wh, add bias, write output in the detected dtype.
__global__ __launch_bounds__(256) void gat_kernel(
    const void* __restrict__ adjv, const float* __restrict__ Wh,
    const float* __restrict__ esrc, const float* __restrict__ edst,
    const void* __restrict__ biasv, const int* __restrict__ cnts,
    void* __restrict__ outv)
{
    __shared__ int   nbr[MAXK];
    __shared__ float sc[MAXK * H];
    __shared__ float inv_s[H];
    __shared__ int   cnt;

    const int i = blockIdx.x, t = threadIdx.x;
    if (t == 0) cnt = 0;
    __syncthreads();

    const int amode = adj_mode_of(cnts);
    auto push = [&](int j) { int p = atomicAdd(&cnt, 1); if (p < MAXK) nbr[p] = j; };

    if (amode == 0) {
        const int4* row = (const int4*)((const uint32_t*)adjv + (size_t)i * N_NODES);
        for (int c = t; c < N_NODES / 4; c += 256) {
            int4 v = row[c]; int j0 = c * 4;
            if (v.x != 0 && j0     != i) push(j0);
            if (v.y != 0 && j0 + 1 != i) push(j0 + 1);
            if (v.z != 0 && j0 + 2 != i) push(j0 + 2);
            if (v.w != 0 && j0 + 3 != i) push(j0 + 3);
        }
    } else if (amode == 1) {
        const int4* row = (const int4*)((const uint16_t*)adjv + (size_t)i * N_NODES);
        for (int c = t; c < N_NODES / 8; c += 256) {
            int4 v = row[c]; int j0 = c * 8;
            uint32_t w[4] = {(uint32_t)v.x, (uint32_t)v.y, (uint32_t)v.z, (uint32_t)v.w};
            for (int q = 0; q < 4; ++q) {
                int b0 = j0 + 2 * q;
                if ((w[q] & 0xFFFFu) && b0     != i) push(b0);
                if ((w[q] >> 16)     && b0 + 1 != i) push(b0 + 1);
            }
        }
    } else {
        const int4* row = (const int4*)((const uint8_t*)adjv + (size_t)i * N_NODES);
        for (int c = t; c < N_NODES / 16; c += 256) {
            int4 v = row[c]; int j0 = c * 16;
            uint32_t w[4] = {(uint32_t)v.x, (uint32_t)v.y, (uint32_t)v.z, (uint32_t)v.w};
            for (int q = 0; q < 4; ++q) {
                uint32_t u = w[q]; int b0 = j0 + 4 * q;
                if ((u & 0x000000FFu) && b0     != i) push(b0);
                if ((u & 0x0000FF00u) && b0 + 1 != i) push(b0 + 1);
                if ((u & 0x00FF0000u) && b0 + 2 != i) push(b0 + 2);
                if ((u & 0xFF000000u) && b0 + 3 != i) push(b0 + 3);
            }
        }
    }
    if (t == 0) push(i);  // self-loop (j==i skipped above, so exactly once)
    __syncthreads();
    const int K = cnt < MAXK ? cnt : MAXK;

    const float* esrc_i = esrc + (size_t)i * H;
    for (int idx = t; idx < K * H; idx += 256) {
        int k = idx >> 3, h = idx & 7;
        float s = esrc_i[h] + edst[(size_t)nbr[k] * H + h];
        sc[idx] = s >= 0.f ? s : 0.2f * s;
    }
    __syncthreads();

    if (t < H) {
        float m = -1e30f;
        for (int k = 0; k < K; ++k) m = fmaxf(m, sc[k * H + t]);
        float sum = 0.f;
        for (int k = 0; k < K; ++k) {
            float e = __expf(sc[k * H + t] - m);
            sc[k * H + t] = e;
            sum += e;
        }
        inv_s[t] = 1.f / sum;
    }
    __syncthreads();

    const int h = t >> 5;
    float acc = 0.f;
    for (int k = 0; k < K; ++k)
        acc += sc[k * H + h] * Wh[(size_t)nbr[k] * HF + t];

    const int f32m = is_f32_mode(cnts);
    float bias = f32m ? ((const float*)biasv)[t] : b2f(((const bf16*)biasv)[t]);
    float o = acc * inv_s[h] + bias;
    if (f32m) ((float*)outv)[(size_t)i * HF + t] = o;
    else      ((bf16*)outv)[(size_t)i * HF + t] = __float2bfloat16(o);
}

extern "C" void kernel_launch(void* const* d_in, const int* in_sizes, int n_in,
                              void* d_out, int out_size, void* d_ws, size_t ws_size,
                              hipStream_t stream) {
    const void* x     = d_in[0];
    const void* adj   = d_in[1];
    const void* W     = d_in[2];
    const void* a_src = d_in[3];
    const void* a_dst = d_in[4];
    const void* bias  = d_in[5];

    int*   cnts = (int*)d_ws;                                  // 4 ints
    float* Wh   = (float*)((char*)d_ws + 256);                 // 4096*256 f32 = 4 MB
    float* esrc = Wh + (size_t)N_NODES * HF;                   // 4096*8 f32
    float* edst = esrc + (size_t)N_NODES * H;                  // 4096*8 f32

    hipMemsetAsync(cnts, 0, 4 * sizeof(int), stream);
    detect_kernel<<<16, 256, 0, stream>>>((const uint16_t*)x, (const uint32_t*)adj, cnts);
    wh_kernel<<<N_NODES / NPB, 256, 0, stream>>>(x, W, a_src, a_dst, cnts, Wh, esrc, edst);
    gat_kernel<<<N_NODES, 256, 0, stream>>>(adj, Wh, esrc, edst, bias, cnts, d_out);
}

// Round 3
// 146.955 us; speedup vs baseline: 1.0175x; 1.0175x over previous
//
#include <hip/hip_runtime.h>
#include <hip/hip_bf16.h>
#include <stdint.h>

#define N_NODES 4096
#define IN_F 256
#define OUT_F 32
#define H 8
#define HF 256   // H*OUT_F
#define NPB 8    // nodes per block in wh_kernel
#define MAXK 128 // max neighbors per row (mean ~17)

typedef __hip_bfloat16 bf16;
__device__ __forceinline__ float b2f(bf16 v) { return __bfloat162float(v); }

// modes word: bit0 = floats are f32 (else bf16); bits[2:1] = adjacency mode
//   amode 0 = 4-byte elems (int32 0/1 or f32 0.0/1.0)
//   amode 1 = 2-byte elems (bf16 0/1)
//   amode 2 = 1-byte elems (bool bytes)
__global__ __launch_bounds__(256) void detect_kernel(
    const uint16_t* __restrict__ x, const uint32_t* __restrict__ adj,
    int* __restrict__ modes)
{
    __shared__ int s[4];
    const int t = threadIdx.x;
    if (t < 4) s[t] = 0;
    __syncthreads();
    int wild = 0, E = 0, F = 0, G = 0;
    // x wildness test: f32 data viewed as bf16 has ~40% |v|>100/NaN halves
    for (int i = t; i < 2048; i += 256) {
        uint16_t u = x[i];
        bf16 v = *(bf16*)&u;
        float f = b2f(v);
        if (!(fabsf(f) < 100.0f)) wild++;
    }
    // adjacency structure over first 64 KB (>=16k elems, ~65 nonzero whp)
    for (int i = t; i < 16384; i += 256) {
        uint32_t w = adj[i];
        if ((w >> 8) != 0) E++;
        uint32_t lo = w & 0xFFFFu, hi = w >> 16;
        if (lo == 0x3F80u || hi == 0x3F80u) F++;
        if (lo != 0) G++;
    }
    if (wild) atomicAdd(&s[0], wild);
    if (E)    atomicAdd(&s[1], E);
    if (F)    atomicAdd(&s[2], F);
    if (G)    atomicAdd(&s[3], G);
    __syncthreads();
    if (t == 0) {
        int f32m = s[0] > 32;
        int amode;
        if (s[1] == 0)                 amode = 0; // only byte0 ever set -> int32
        else if (s[2] > 0 && s[3]==0)  amode = 0; // f32 1.0 pattern
        else if (s[2] > 0)             amode = 1; // bf16 1.0 at even halfwords
        else                           amode = 2; // plain bytes
        modes[0] = f32m | (amode << 1);
    }
}

// Wh[n][h*32+f] = sum_i x[n][i] * W[h][i][f]  (fp32 into ws),
// plus e_src[n][h], e_dst[n][h] via 32-lane shuffle reduction.
__global__ __launch_bounds__(256) void wh_kernel(
    const void* __restrict__ xv, const void* __restrict__ Wv,
    const void* __restrict__ asv, const void* __restrict__ adv,
    const int* __restrict__ modes,
    float* __restrict__ Wh, float* __restrict__ esrc, float* __restrict__ edst)
{
    __shared__ float xl[NPB][IN_F];
    const int t = threadIdx.x;
    const int n0 = blockIdx.x * NPB;
    const int f32m = modes[0] & 1;

    if (f32m) {
        const float* x = (const float*)xv;
        #pragma unroll
        for (int r = 0; r < NPB; ++r) xl[r][t] = x[(size_t)(n0 + r) * IN_F + t];
    } else {
        const bf16* x = (const bf16*)xv;
        #pragma unroll
        for (int r = 0; r < NPB; ++r) xl[r][t] = b2f(x[(size_t)(n0 + r) * IN_F + t]);
    }
    __syncthreads();

    const int h = t >> 5, f = t & 31;
    float acc[NPB];
    #pragma unroll
    for (int r = 0; r < NPB; ++r) acc[r] = 0.f;

    if (f32m) {
        const float* Wp = (const float*)Wv + (size_t)h * IN_F * OUT_F + f;
        #pragma unroll 8
        for (int i = 0; i < IN_F; ++i) {
            float w = Wp[i * OUT_F];
            #pragma unroll
            for (int r = 0; r < NPB; ++r) acc[r] += xl[r][i] * w;
        }
    } else {
        const bf16* Wp = (const bf16*)Wv + (size_t)h * IN_F * OUT_F + f;
        #pragma unroll 8
        for (int i = 0; i < IN_F; ++i) {
            float w = b2f(Wp[i * OUT_F]);
            #pragma unroll
            for (int r = 0; r < NPB; ++r) acc[r] += xl[r][i] * w;
        }
    }

    float as, ad;
    if (f32m) { as = ((const float*)asv)[t]; ad = ((const float*)adv)[t]; }
    else      { as = b2f(((const bf16*)asv)[t]); ad = b2f(((const bf16*)adv)[t]); }

    #pragma unroll
    for (int r = 0; r < NPB; ++r) {
        Wh[(size_t)(n0 + r) * HF + t] = acc[r];
        float vs = acc[r] * as, vd = acc[r] * ad;
        for (int off = 16; off > 0; off >>= 1) {
            vs += __shfl_down(vs, off, 32);
            vd += __shfl_down(vd, off, 32);
        }
        if (f == 0) {
            esrc[(size_t)(n0 + r) * H + h] = vs;
            edst[(size_t)(n0 + r) * H + h] = vd;
        }
    }
}

// Per row i: gather neighbor list, per-head softmax over ~17 logits,
// aggregate alpha*Wh, add bias, write output in the detected dtype.
__global__ __launch_bounds__(256) void gat_kernel(
    const void* __restrict__ adjv, const float* __restrict__ Wh,
    const float* __restrict__ esrc, const float* __restrict__ edst,
    const void* __restrict__ biasv, const int* __restrict__ modes,
    void* __restrict__ outv)
{
    __shared__ int   nbr[MAXK];
    __shared__ float sc[MAXK * H];
    __shared__ float inv_s[H];
    __shared__ int   cnt;

    const int i = blockIdx.x, t = threadIdx.x;
    if (t == 0) cnt = 0;
    __syncthreads();

    const int m = modes[0];
    const int amode = m >> 1;
    auto push = [&](int j) { int p = atomicAdd(&cnt, 1); if (p < MAXK) nbr[p] = j; };

    if (amode == 0) {
        const int4* row = (const int4*)((const uint32_t*)adjv + (size_t)i * N_NODES);
        for (int c = t; c < N_NODES / 4; c += 256) {
            int4 v = row[c]; int j0 = c * 4;
            if (v.x != 0 && j0     != i) push(j0);
            if (v.y != 0 && j0 + 1 != i) push(j0 + 1);
            if (v.z != 0 && j0 + 2 != i) push(j0 + 2);
            if (v.w != 0 && j0 + 3 != i) push(j0 + 3);
        }
    } else if (amode == 1) {
        const int4* row = (const int4*)((const uint16_t*)adjv + (size_t)i * N_NODES);
        for (int c = t; c < N_NODES / 8; c += 256) {
            int4 v = row[c]; int j0 = c * 8;
            uint32_t w[4] = {(uint32_t)v.x, (uint32_t)v.y, (uint32_t)v.z, (uint32_t)v.w};
            #pragma unroll
            for (int q = 0; q < 4; ++q) {
                int b0 = j0 + 2 * q;
                if ((w[q] & 0xFFFFu) && b0     != i) push(b0);
                if ((w[q] >> 16)     && b0 + 1 != i) push(b0 + 1);
            }
        }
    } else {
        const int4* row = (const int4*)((const uint8_t*)adjv + (size_t)i * N_NODES);
        for (int c = t; c < N_NODES / 16; c += 256) {
            int4 v = row[c]; int j0 = c * 16;
            uint32_t w[4] = {(uint32_t)v.x, (uint32_t)v.y, (uint32_t)v.z, (uint32_t)v.w};
            #pragma unroll
            for (int q = 0; q < 4; ++q) {
                uint32_t u = w[q]; int b0 = j0 + 4 * q;
                if ((u & 0x000000FFu) && b0     != i) push(b0);
                if ((u & 0x0000FF00u) && b0 + 1 != i) push(b0 + 1);
                if ((u & 0x00FF0000u) && b0 + 2 != i) push(b0 + 2);
                if ((u & 0xFF000000u) && b0 + 3 != i) push(b0 + 3);
            }
        }
    }
    if (t == 0) push(i);  // self-loop (j==i skipped above, so exactly once)
    __syncthreads();
    const int K = cnt < MAXK ? cnt : MAXK;

    const float* esrc_i = esrc + (size_t)i * H;
    for (int idx = t; idx < K * H; idx += 256) {
        int k = idx >> 3, h = idx & 7;
        float s = esrc_i[h] + edst[(size_t)nbr[k] * H + h];
        sc[idx] = s >= 0.f ? s : 0.2f * s;
    }
    __syncthreads();

    if (t < H) {
        float mx = -1e30f;
        for (int k = 0; k < K; ++k) mx = fmaxf(mx, sc[k * H + t]);
        float sum = 0.f;
        for (int k = 0; k < K; ++k) {
            float e = __expf(sc[k * H + t] - mx);
            sc[k * H + t] = e;
            sum += e;
        }
        inv_s[t] = 1.f / sum;
    }
    __syncthreads();

    const int h = t >> 5;
    float acc = 0.f;
    #pragma unroll 4
    for (int k = 0; k < K; ++k)
        acc += sc[k * H + h] * Wh[(size_t)nbr[k] * HF + t];

    const int f32m = m & 1;
    float bias = f32m ? ((const float*)biasv)[t] : b2f(((const bf16*)biasv)[t]);
    float o = acc * inv_s[h] + bias;
    if (f32m) ((float*)outv)[(size_t)i * HF + t] = o;
    else      ((bf16*)outv)[(size_t)i * HF + t] = __float2bfloat16(o);
}

extern "C" void kernel_launch(void* const* d_in, const int* in_sizes, int n_in,
                              void* d_out, int out_size, void* d_ws, size_t ws_size,
                              hipStream_t stream) {
    const void* x     = d_in[0];
    const void* adj   = d_in[1];
    const void* W     = d_in[2];
    const void* a_src = d_in[3];
    const void* a_dst = d_in[4];
    const void* bias  = d_in[5];

    int*   modes = (int*)d_ws;                                 // 1 int
    float* Wh    = (float*)((char*)d_ws + 256);                // 4096*256 f32 = 4 MB
    float* esrc  = Wh + (size_t)N_NODES * HF;                  // 4096*8 f32
    float* edst  = esrc + (size_t)N_NODES * H;                 // 4096*8 f32

    detect_kernel<<<1, 256, 0, stream>>>((const uint16_t*)x, (const uint32_t*)adj, modes);
    wh_kernel<<<N_NODES / NPB, 256, 0, stream>>>(x, W, a_src, a_dst, modes, Wh, esrc, edst);
    gat_kernel<<<N_NODES, 256, 0, stream>>>(adj, Wh, esrc, edst, bias, modes, d_out);
}

// Round 4
// 137.570 us; speedup vs baseline: 1.0869x; 1.0682x over previous
//
#include <hip/hip_runtime.h>
#include <hip/hip_bf16.h>
#include <stdint.h>

#define N_NODES 4096
#define IN_F 256
#define OUT_F 32
#define H 8
#define HF 256    // H*OUT_F
#define NPB 16    // nodes per block in wh_kernel
#define XPAD 20   // padded leading dim for transposed x tile (16 + 4)
#define MAXK 128  // max neighbors per row (mean ~17)

typedef __hip_bfloat16 bf16;
__device__ __forceinline__ float b2f(bf16 v) { return __bfloat162float(v); }

// Per-block float-mode self-detection: u16 view of x[0..63]. f32 data viewed
// as bf16 halves has ~47% wild (|v|>100 or NaN) low-mantissa halves; genuine
// bf16 N(0,1) data has none.
__device__ __forceinline__ int detect_f32m(const void* xv, int t) {
    uint16_t u = ((const uint16_t*)xv)[t & 63];
    bf16 v = *(bf16*)&u;
    float f = b2f(v);
    int wild = !(fabsf(f) < 100.0f);
    unsigned long long ball = __ballot(wild);
    return __popcll(ball) > 4;
}

// wh_kernel: grid 257. Blocks 0..255: Wh[n][h*32+f] = sum_i x[n][i]*W[h][i][f]
// with 4x4 register blocking (wave -> 4-node group, lane -> 4-col group);
// also e_src[n][h], e_dst[n][h] via width-8 shuffle reduction.
// Block 256: adjacency dtype detection only, writes modes[0] for gat_kernel.
__global__ __launch_bounds__(256) void wh_kernel(
    const void* __restrict__ xv, const void* __restrict__ Wv,
    const void* __restrict__ asv, const void* __restrict__ adv,
    const uint32_t* __restrict__ adj, int* __restrict__ modes,
    float* __restrict__ Wh, float* __restrict__ esrc, float* __restrict__ edst)
{
    const int t = threadIdx.x;
    const int f32m = detect_f32m(xv, t);

    if (blockIdx.x == 256) {
        // modes word: bit0 = f32 floats; bits[2:1] = adjacency element width
        // amode 0 = 4-byte (int32 0/1 or f32 1.0), 1 = 2-byte (bf16), 2 = bytes
        __shared__ int s[4];
        if (t < 4) s[t] = 0;
        __syncthreads();
        int E = 0, F = 0, G = 0;
        for (int i = t; i < 16384; i += 256) {
            uint32_t w = adj[i];
            if ((w >> 8) != 0) E++;
            uint32_t lo = w & 0xFFFFu, hi = w >> 16;
            if (lo == 0x3F80u || hi == 0x3F80u) F++;
            if (lo != 0) G++;
        }
        if (E) atomicAdd(&s[1], E);
        if (F) atomicAdd(&s[2], F);
        if (G) atomicAdd(&s[3], G);
        __syncthreads();
        if (t == 0) {
            int amode;
            if (s[1] == 0)               amode = 0; // only byte0 set -> int32
            else if (s[2] > 0 && !s[3])  amode = 0; // f32 1.0 pattern
            else if (s[2] > 0)           amode = 1; // bf16 1.0 at even halves
            else                         amode = 2; // plain bytes
            modes[0] = f32m | (amode << 1);
        }
        return;
    }

    __shared__ float xl[IN_F][XPAD];  // transposed tile: xl[i][r], padded
    const int n0 = blockIdx.x * NPB;

    // Stage x[n0..n0+15][:] transposed (global reads coalesced over i=t).
    if (f32m) {
        const float* x = (const float*)xv + (size_t)n0 * IN_F;
        #pragma unroll
        for (int r = 0; r < NPB; ++r) xl[t][r] = x[(size_t)r * IN_F + t];
    } else {
        const bf16* x = (const bf16*)xv + (size_t)n0 * IN_F;
        #pragma unroll
        for (int r = 0; r < NPB; ++r) xl[t][r] = b2f(x[(size_t)r * IN_F + t]);
    }
    __syncthreads();

    const int rg = t >> 6;        // wave id -> nodes rg*4 .. rg*4+3
    const int cg = t & 63;        // lane  -> cols cg*4 .. cg*4+3
    const int h  = cg >> 3;
    const int f0 = (cg & 7) * 4;

    float acc[4][4];
    #pragma unroll
    for (int r = 0; r < 4; ++r)
        #pragma unroll
        for (int j = 0; j < 4; ++j) acc[r][j] = 0.f;

    if (f32m) {
        const float* Wp = (const float*)Wv + (size_t)h * IN_F * OUT_F + f0;
        #pragma unroll 4
        for (int i = 0; i < IN_F; ++i) {
            const float4 w4 = *(const float4*)&Wp[(size_t)i * OUT_F];
            const float4 x4 = *(const float4*)&xl[i][rg * 4];  // wave-uniform
            const float xs[4] = {x4.x, x4.y, x4.z, x4.w};
            #pragma unroll
            for (int r = 0; r < 4; ++r) {
                acc[r][0] += xs[r] * w4.x;
                acc[r][1] += xs[r] * w4.y;
                acc[r][2] += xs[r] * w4.z;
                acc[r][3] += xs[r] * w4.w;
            }
        }
    } else {
        const bf16* Wp = (const bf16*)Wv + (size_t)h * IN_F * OUT_F + f0;
        #pragma unroll 4
        for (int i = 0; i < IN_F; ++i) {
            const ushort4 wu = *(const ushort4*)&Wp[(size_t)i * OUT_F];
            float w0 = b2f(*(bf16*)&wu.x), w1 = b2f(*(bf16*)&wu.y);
            float w2 = b2f(*(bf16*)&wu.z), w3 = b2f(*(bf16*)&wu.w);
            const float4 x4 = *(const float4*)&xl[i][rg * 4];
            const float xs[4] = {x4.x, x4.y, x4.z, x4.w};
            #pragma unroll
            for (int r = 0; r < 4; ++r) {
                acc[r][0] += xs[r] * w0;
                acc[r][1] += xs[r] * w1;
                acc[r][2] += xs[r] * w2;
                acc[r][3] += xs[r] * w3;
            }
        }
    }

    // a_src/a_dst for this thread's 4 columns
    float as0, as1, as2, as3, ad0, ad1, ad2, ad3;
    if (f32m) {
        const float4 a4 = *(const float4*)&((const float*)asv)[h * OUT_F + f0];
        const float4 b4 = *(const float4*)&((const float*)adv)[h * OUT_F + f0];
        as0 = a4.x; as1 = a4.y; as2 = a4.z; as3 = a4.w;
        ad0 = b4.x; ad1 = b4.y; ad2 = b4.z; ad3 = b4.w;
    } else {
        const ushort4 a4 = *(const ushort4*)&((const bf16*)asv)[h * OUT_F + f0];
        const ushort4 b4 = *(const ushort4*)&((const bf16*)adv)[h * OUT_F + f0];
        as0 = b2f(*(bf16*)&a4.x); as1 = b2f(*(bf16*)&a4.y);
        as2 = b2f(*(bf16*)&a4.z); as3 = b2f(*(bf16*)&a4.w);
        ad0 = b2f(*(bf16*)&b4.x); ad1 = b2f(*(bf16*)&b4.y);
        ad2 = b2f(*(bf16*)&b4.z); ad3 = b2f(*(bf16*)&b4.w);
    }

    #pragma unroll
    for (int r = 0; r < 4; ++r) {
        const int n = n0 + rg * 4 + r;
        // Wh write: float4, coalesced per wave
        *(float4*)&Wh[(size_t)n * HF + cg * 4] =
            make_float4(acc[r][0], acc[r][1], acc[r][2], acc[r][3]);
        float vs = acc[r][0] * as0 + acc[r][1] * as1 + acc[r][2] * as2 + acc[r][3] * as3;
        float vd = acc[r][0] * ad0 + acc[r][1] * ad1 + acc[r][2] * ad2 + acc[r][3] * ad3;
        // reduce across the 8 lanes (cg&7) sharing this (n, h)
        vs += __shfl_down(vs, 4, 8); vs += __shfl_down(vs, 2, 8); vs += __shfl_down(vs, 1, 8);
        vd += __shfl_down(vd, 4, 8); vd += __shfl_down(vd, 2, 8); vd += __shfl_down(vd, 1, 8);
        if ((cg & 7) == 0) {
            esrc[(size_t)n * H + h] = vs;
            edst[(size_t)n * H + h] = vd;
        }
    }
}

// Per row i: gather neighbor list, per-head softmax over ~17 logits,
// aggregate alpha*Wh, add bias, write output in the detected dtype.
__global__ __launch_bounds__(256) void gat_kernel(
    const void* __restrict__ adjv, const float* __restrict__ Wh,
    const float* __restrict__ esrc, const float* __restrict__ edst,
    const void* __restrict__ biasv, const int* __restrict__ modes,
    void* __restrict__ outv)
{
    __shared__ int   nbr[MAXK];
    __shared__ float sc[MAXK * H];
    __shared__ float inv_s[H];
    __shared__ int   cnt;

    const int i = blockIdx.x, t = threadIdx.x;
    if (t == 0) cnt = 0;
    __syncthreads();

    const int m = modes[0];
    const int amode = m >> 1;
    auto push = [&](int j) { int p = atomicAdd(&cnt, 1); if (p < MAXK) nbr[p] = j; };

    if (amode == 0) {
        const int4* row = (const int4*)((const uint32_t*)adjv + (size_t)i * N_NODES);
        for (int c = t; c < N_NODES / 4; c += 256) {
            int4 v = row[c]; int j0 = c * 4;
            if (v.x != 0 && j0     != i) push(j0);
            if (v.y != 0 && j0 + 1 != i) push(j0 + 1);
            if (v.z != 0 && j0 + 2 != i) push(j0 + 2);
            if (v.w != 0 && j0 + 3 != i) push(j0 + 3);
        }
    } else if (amode == 1) {
        const int4* row = (const int4*)((const uint16_t*)adjv + (size_t)i * N_NODES);
        for (int c = t; c < N_NODES / 8; c += 256) {
            int4 v = row[c]; int j0 = c * 8;
            uint32_t w[4] = {(uint32_t)v.x, (uint32_t)v.y, (uint32_t)v.z, (uint32_t)v.w};
            #pragma unroll
            for (int q = 0; q < 4; ++q) {
                int b0 = j0 + 2 * q;
                if ((w[q] & 0xFFFFu) && b0     != i) push(b0);
                if ((w[q] >> 16)     && b0 + 1 != i) push(b0 + 1);
            }
        }
    } else {
        const int4* row = (const int4*)((const uint8_t*)adjv + (size_t)i * N_NODES);
        for (int c = t; c < N_NODES / 16; c += 256) {
            int4 v = row[c]; int j0 = c * 16;
            uint32_t w[4] = {(uint32_t)v.x, (uint32_t)v.y, (uint32_t)v.z, (uint32_t)v.w};
            #pragma unroll
            for (int q = 0; q < 4; ++q) {
                uint32_t u = w[q]; int b0 = j0 + 4 * q;
                if ((u & 0x000000FFu) && b0     != i) push(b0);
                if ((u & 0x0000FF00u) && b0 + 1 != i) push(b0 + 1);
                if ((u & 0x00FF0000u) && b0 + 2 != i) push(b0 + 2);
                if ((u & 0xFF000000u) && b0 + 3 != i) push(b0 + 3);
            }
        }
    }
    if (t == 0) push(i);  // self-loop (j==i skipped above, so exactly once)
    __syncthreads();
    const int K = cnt < MAXK ? cnt : MAXK;

    const float* esrc_i = esrc + (size_t)i * H;
    for (int idx = t; idx < K * H; idx += 256) {
        int k = idx >> 3, h = idx & 7;
        float s = esrc_i[h] + edst[(size_t)nbr[k] * H + h];
        sc[idx] = s >= 0.f ? s : 0.2f * s;
    }
    __syncthreads();

    if (t < H) {
        float mx = -1e30f;
        for (int k = 0; k < K; ++k) mx = fmaxf(mx, sc[k * H + t]);
        float sum = 0.f;
        for (int k = 0; k < K; ++k) {
            float e = __expf(sc[k * H + t] - mx);
            sc[k * H + t] = e;
            sum += e;
        }
        inv_s[t] = 1.f / sum;
    }
    __syncthreads();

    const int h = t >> 5;
    float acc = 0.f;
    #pragma unroll 4
    for (int k = 0; k < K; ++k)
        acc += sc[k * H + h] * Wh[(size_t)nbr[k] * HF + t];

    const int f32m = m & 1;
    float bias = f32m ? ((const float*)biasv)[t] : b2f(((const bf16*)biasv)[t]);
    float o = acc * inv_s[h] + bias;
    if (f32m) ((float*)outv)[(size_t)i * HF + t] = o;
    else      ((bf16*)outv)[(size_t)i * HF + t] = __float2bfloat16(o);
}

extern "C" void kernel_launch(void* const* d_in, const int* in_sizes, int n_in,
                              void* d_out, int out_size, void* d_ws, size_t ws_size,
                              hipStream_t stream) {
    const void* x     = d_in[0];
    const void* adj   = d_in[1];
    const void* W     = d_in[2];
    const void* a_src = d_in[3];
    const void* a_dst = d_in[4];
    const void* bias  = d_in[5];

    int*   modes = (int*)d_ws;                                 // 1 int
    float* Wh    = (float*)((char*)d_ws + 256);                // 4096*256 f32 = 4 MB
    float* esrc  = Wh + (size_t)N_NODES * HF;                  // 4096*8 f32
    float* edst  = esrc + (size_t)N_NODES * H;                 // 4096*8 f32

    wh_kernel<<<N_NODES / NPB + 1, 256, 0, stream>>>(
        x, W, a_src, a_dst, (const uint32_t*)adj, modes, Wh, esrc, edst);
    gat_kernel<<<N_NODES, 256, 0, stream>>>(adj, Wh, esrc, edst, bias, modes, d_out);
}